// Round 16
// baseline (80.804 us; speedup 1.0000x reference)
//
#include <hip/hip_runtime.h>
#include <hip/hip_bf16.h>

#define NSEN 4000
#define NP   4096
#define DIN  128
#define DOUT 128
#define EDIM 16
#define BATCH 8

typedef __attribute__((ext_vector_type(8))) short bf16x8;
typedef __attribute__((ext_vector_type(4))) float f32x4;

__device__ __forceinline__ unsigned short f2bf(float f) {
  unsigned int u = __float_as_uint(f);
  unsigned int r = (u + 0x7FFFu + ((u >> 16) & 1u)) >> 16;
  return (unsigned short)r;
}
__device__ __forceinline__ float bf2f(unsigned short s) {
  unsigned int u = ((unsigned int)s) << 16;
  return __uint_as_float(u);
}

__device__ __forceinline__ void gl_lds16(const void* g, void* l) {
  __builtin_amdgcn_global_load_lds((const __attribute__((address_space(1))) void*)g,
                                   (__attribute__((address_space(3))) void*)l, 16, 0, 0);
}

// ---------------- Kernel 1 (merged prep, R13-proven) ------------------------------
// blocks 0..249:   P = exp(relu(E1 @ E2^T)) unnorm -> adjp bf16 ; rinv = 1/rowsum
// blocks 250..505: yt[b*128+o][m] = bf16( (x @ W)[b,m,o] ), cols m>=NSEN -> 0
__global__ __launch_bounds__(512) void k_prep(const float* __restrict__ E1,
                                              const float* __restrict__ E2,
                                              const float* __restrict__ W,
                                              const float* __restrict__ x,
                                              unsigned short* __restrict__ adjp,
                                              float* __restrict__ rinv,
                                              unsigned short* __restrict__ yt) {
  __shared__ float rsum[8][16];
  __shared__ __align__(16) unsigned short pool[34816];
  const int bx = blockIdx.x;
  const int tid = threadIdx.x;
  const int lane = tid & 63, wv = tid >> 6;
  const int lr = lane & 15, lq = lane >> 4;

  if (bx >= 250) {
    unsigned short* wlds = pool;            // [128][136] W^T bf16
    unsigned short* ylds = pool + 17408;    // [128][136] y^T bf16
    {
      const int fr = tid >> 5;
      const int o4 = tid & 31;
#pragma unroll
      for (int r8 = 0; r8 < 8; r8++) {
        const int f = fr + r8 * 16;
        float4 w4 = *(const float4*)&W[(size_t)f * DOUT + o4 * 4];
        wlds[(o4 * 4 + 0) * 136 + f] = f2bf(w4.x);
        wlds[(o4 * 4 + 1) * 136 + f] = f2bf(w4.y);
        wlds[(o4 * 4 + 2) * 136 + f] = f2bf(w4.z);
        wlds[(o4 * 4 + 3) * 136 + f] = f2bf(w4.w);
      }
    }
    __syncthreads();

    const int yi = bx - 250;
    const int b  = yi >> 5;
    const int m0 = (yi & 31) * 128;
    const int mh = wv >> 2;
    const int os = wv & 3;

    bf16x8 af[2][4];
#pragma unroll
    for (int ot = 0; ot < 2; ot++) {
      const int ob = os * 32 + ot * 16 + lr;
#pragma unroll
      for (int ks = 0; ks < 4; ks++)
        af[ot][ks] = *(const bf16x8*)&wlds[ob * 136 + ks * 32 + lq * 8];
    }

#pragma unroll
    for (int mt = 0; mt < 4; mt++) {
      const int mloc = mh * 64 + mt * 16;
      const int m = m0 + mloc + lr;
      bf16x8 bx8[4];
      if (m < NSEN) {
        const float* xp = &x[((size_t)b * NSEN + m) * DIN + lq * 8];
#pragma unroll
        for (int ks = 0; ks < 4; ks++) {
          float4 v0 = *(const float4*)(xp + ks * 32);
          float4 v1 = *(const float4*)(xp + ks * 32 + 4);
          bx8[ks][0] = (short)f2bf(v0.x); bx8[ks][1] = (short)f2bf(v0.y);
          bx8[ks][2] = (short)f2bf(v0.z); bx8[ks][3] = (short)f2bf(v0.w);
          bx8[ks][4] = (short)f2bf(v1.x); bx8[ks][5] = (short)f2bf(v1.y);
          bx8[ks][6] = (short)f2bf(v1.z); bx8[ks][7] = (short)f2bf(v1.w);
        }
      } else {
#pragma unroll
        for (int ks = 0; ks < 4; ks++)
#pragma unroll
          for (int j = 0; j < 8; j++) bx8[ks][j] = 0;
      }
#pragma unroll
      for (int ot = 0; ot < 2; ot++) {
        f32x4 c = (f32x4){0.f, 0.f, 0.f, 0.f};
#pragma unroll
        for (int ks = 0; ks < 4; ks++)
          c = __builtin_amdgcn_mfma_f32_16x16x32_bf16(af[ot][ks], bx8[ks], c, 0, 0, 0);
#pragma unroll
        for (int i = 0; i < 4; i++)
          ylds[(os * 32 + ot * 16 + lq * 4 + i) * 136 + mloc + lr] = f2bf(c[i]);
      }
    }
    __syncthreads();
#pragma unroll
    for (int s2 = 0; s2 < 4; s2++) {
      int c = s2 * 512 + tid;
      int row = c >> 4;
      int mc = c & 15;
      *(bf16x8*)&yt[(size_t)(b * 128 + row) * NP + m0 + mc * 8] =
          *(const bf16x8*)&ylds[row * 136 + mc * 8];
    }
    return;
  }

  // ---- adjacency rows n0..n0+15 (MFMA hi/lo split, direct stores) ----
  const int n0 = bx * 16;

  float a[8];
  {
    const float* e1p = &E1[(size_t)(n0 + lr) * EDIM + (lq & 1) * 8];
    *(float4*)&a[0] = *(const float4*)e1p;
    *(float4*)&a[4] = *(const float4*)(e1p + 4);
  }
  bf16x8 af1, af2;
#pragma unroll
  for (int j = 0; j < 8; j++) {
    unsigned short hs = f2bf(a[j]);
    af1[j] = (short)hs;
    float lo = a[j] - bf2f(hs);
    af2[j] = (lq < 2) ? (short)f2bf(lo) : (short)0;
  }

  float rs[4] = {0.f, 0.f, 0.f, 0.f};
  for (int t = wv; t < NSEN / 16; t += 8) {
    const int m = t * 16 + lr;
    float bv[8];
    const float* e2p = &E2[(size_t)m * EDIM + (lq & 1) * 8];
    *(float4*)&bv[0] = *(const float4*)e2p;
    *(float4*)&bv[4] = *(const float4*)(e2p + 4);
    bf16x8 bfrag;
#pragma unroll
    for (int j = 0; j < 8; j++) {
      unsigned short hs = f2bf(bv[j]);
      if (lq < 2) bfrag[j] = (short)hs;
      else        bfrag[j] = (short)f2bf(bv[j] - bf2f(hs));
    }
    f32x4 c = (f32x4){0.f, 0.f, 0.f, 0.f};
    c = __builtin_amdgcn_mfma_f32_16x16x32_bf16(af1, bfrag, c, 0, 0, 0);
    c = __builtin_amdgcn_mfma_f32_16x16x32_bf16(af2, bfrag, c, 0, 0, 0);
#pragma unroll
    for (int i = 0; i < 4; i++) {
      float p = __expf(fmaxf(c[i], 0.f));
      rs[i] += p;
      adjp[(size_t)(n0 + lq * 4 + i) * NP + t * 16 + lr] = f2bf(p);
    }
  }
  for (int i = tid; i < 16 * (NP - NSEN); i += 512) {
    int r = i / (NP - NSEN), c = i % (NP - NSEN);
    adjp[(size_t)(n0 + r) * NP + NSEN + c] = 0;
  }
#pragma unroll
  for (int i = 0; i < 4; i++) {
    rs[i] += __shfl_xor(rs[i], 1, 64);
    rs[i] += __shfl_xor(rs[i], 2, 64);
    rs[i] += __shfl_xor(rs[i], 4, 64);
    rs[i] += __shfl_xor(rs[i], 8, 64);
  }
  if (lr == 0) {
#pragma unroll
    for (int i = 0; i < 4; i++) rsum[wv][lq * 4 + i] = rs[i];
  }
  __syncthreads();
  if (tid < 16) {
    float s = 0.f;
#pragma unroll
    for (int w = 0; w < 8; w++) s += rsum[w][tid];
    rinv[n0 + tid] = 1.0f / s;
  }
}

// ---------------- Kernel 2: 256x256 split-K GEMM, BK=32, 3-slot ring --------------
// Depth-2 prefetch (stage it+2 during it), vmcnt(4) never stalls on fresh loads,
// ONE barrier per K-step (3 slots make it sufficient), 2 clusters of 16 MFMA with
// own lgkmcnt(0)+setprio, 2-bit swizzle chunk^=(row^row>>2)&3 (bank-free at 16-lane
// granularity). 8 waves (2Mx4N), wave tile 128x64, 96 KB LDS -> 2 waves/SIMD.
__global__ __launch_bounds__(512, 2) void k_gemm(const unsigned short* __restrict__ A,
                                                 const unsigned short* __restrict__ Bt,
                                                 unsigned short* __restrict__ part,
                                                 int nsteps) {
  __shared__ __align__(16) unsigned short smem[49152];  // 96 KB: A 3x8192 | B 3x8192
  unsigned short* tA0 = smem;            // 3 slots x 8192 shorts (256 rows x 32 k)
  unsigned short* tB0 = smem + 24576;
  const int tid = threadIdx.x;
  const int lane = tid & 63, wv = tid >> 6;
  const int wr = wv >> 2, wcn = wv & 3;   // 2M x 4N waves, wave tile 128x64
  const int lr = lane & 15, lq = lane >> 4;
  const int kh = blockIdx.x >> 4;
  const int m0 = (blockIdx.x & 15) * 256;
  const int n0c = blockIdx.y * 256;
  const int kb0 = kh * nsteps * 32;

  f32x4 acc[8][4];
#pragma unroll
  for (int p = 0; p < 8; p++)
#pragma unroll
    for (int q = 0; q < 4; q++) acc[p][q] = (f32x4){0.f, 0.f, 0.f, 0.f};

  // per-slot staging: A = 1024 chunks (2/thread), B same. row = idx>>2, chunk = idx&3,
  // source chunk pre-swizzled by S(row) = (row ^ row>>2) & 3.
#define STAGE_A(sl, kb, s)                                                              \
  {                                                                                     \
    int idx = (s) * 512 + tid;                                                          \
    int row = idx >> 2;                                                                 \
    int kc = (((idx & 3) ^ ((row ^ (row >> 2)) & 3)) << 3);                             \
    gl_lds16(&A[(size_t)(m0 + row) * NP + (kb) + kc], &tA0[(sl) * 8192 + idx * 8]);     \
  }
#define STAGE_B(sl, kb, s)                                                              \
  {                                                                                     \
    int idx = (s) * 512 + tid;                                                          \
    int row = idx >> 2;                                                                 \
    int kc = (((idx & 3) ^ ((row ^ (row >> 2)) & 3)) << 3);                             \
    gl_lds16(&Bt[(size_t)(n0c + row) * NP + (kb) + kc], &tB0[(sl) * 8192 + idx * 8]);   \
  }

  // prologue: stage tiles 0 and 1
  STAGE_A(0, kb0, 0) STAGE_A(0, kb0, 1) STAGE_B(0, kb0, 0) STAGE_B(0, kb0, 1)
  STAGE_A(1, kb0 + 32, 0) STAGE_A(1, kb0 + 32, 1) STAGE_B(1, kb0 + 32, 0) STAGE_B(1, kb0 + 32, 1)

  // lane-invariant read swizzle: S(row)=(lr&3)^((lr>>2)&3) for all our row bases
  const int koff = ((lq ^ ((lr & 3) ^ ((lr >> 2) & 3))) << 3);

  int cur = 0;
  for (int it = 0; it < nsteps; ++it) {
    if (it < nsteps - 1) {
      asm volatile("s_waitcnt vmcnt(4)" ::: "memory");  // tile it landed; it+1 in flight
    } else {
      asm volatile("s_waitcnt vmcnt(0)" ::: "memory");
    }
    __builtin_amdgcn_s_barrier();  // all waves' tile-it loads visible; slot (it+2)%3 free

    int s2 = cur + 2; if (s2 >= 3) s2 -= 3;
    const int kbn = kb0 + (it + 2) * 32;
    const bool pf = (it + 2 < nsteps);
    const unsigned short* aslot = &tA0[cur * 8192];
    const unsigned short* bslot = &tB0[cur * 8192];

    bf16x8 bfr[4];
    {  // cluster 1: p0-3 x q0-3
      if (pf) { STAGE_A(s2, kbn, 0) STAGE_A(s2, kbn, 1) }
      bf16x8 af[4];
#pragma unroll
      for (int p = 0; p < 4; p++)
        af[p] = *(const bf16x8*)&aslot[(wr * 128 + p * 16 + lr) * 32 + koff];
#pragma unroll
      for (int q = 0; q < 4; q++)
        bfr[q] = *(const bf16x8*)&bslot[(wcn * 64 + q * 16 + lr) * 32 + koff];
      asm volatile("s_waitcnt lgkmcnt(0)" ::: "memory");
      __builtin_amdgcn_sched_barrier(0);
      __builtin_amdgcn_s_setprio(1);
#pragma unroll
      for (int p = 0; p < 4; p++)
#pragma unroll
        for (int q = 0; q < 4; q++)
          acc[p][q] = __builtin_amdgcn_mfma_f32_16x16x32_bf16(af[p], bfr[q], acc[p][q], 0, 0, 0);
      __builtin_amdgcn_s_setprio(0);
    }
    {  // cluster 2: p4-7 x q0-3 (B reused in registers)
      if (pf) { STAGE_B(s2, kbn, 0) STAGE_B(s2, kbn, 1) }
      bf16x8 af[4];
#pragma unroll
      for (int p = 0; p < 4; p++)
        af[p] = *(const bf16x8*)&aslot[(wr * 128 + (4 + p) * 16 + lr) * 32 + koff];
      asm volatile("s_waitcnt lgkmcnt(0)" ::: "memory");
      __builtin_amdgcn_sched_barrier(0);
      __builtin_amdgcn_s_setprio(1);
#pragma unroll
      for (int p = 0; p < 4; p++)
#pragma unroll
        for (int q = 0; q < 4; q++)
          acc[4 + p][q] = __builtin_amdgcn_mfma_f32_16x16x32_bf16(af[p], bfr[q], acc[4 + p][q], 0, 0, 0);
      __builtin_amdgcn_s_setprio(0);
    }
    cur = cur + 1; if (cur >= 3) cur = 0;
  }
#undef STAGE_A
#undef STAGE_B

  // epilogue: bf16 partial store part[kh][m][j]
  unsigned short* pdst = part + ((size_t)kh << 22);
#pragma unroll
  for (int p = 0; p < 8; p++)
#pragma unroll
    for (int q = 0; q < 4; q++) {
      const int col = n0c + wcn * 64 + q * 16 + lr;
#pragma unroll
      for (int i = 0; i < 4; i++) {
        const int row = m0 + wr * 128 + p * 16 + lq * 4 + i;
        pdst[(size_t)row * 1024 + col] = f2bf(acc[p][q][i]);
      }
    }
}

// ---------------- Kernel 3: out = relu((sum_kh part)*rinv + bias) -----------------
__global__ __launch_bounds__(256) void k_fin(const unsigned short* __restrict__ part,
                                             const float* __restrict__ rinv,
                                             const float* __restrict__ bias,
                                             float* __restrict__ out, int ksl) {
  const int tid = threadIdx.x;
  const int nl = tid >> 4;
  const int ch = tid & 15;
  const int n  = blockIdx.x * 16 + nl;   // < 4000
  const int b  = blockIdx.y;
  const int j  = b * 128 + ch * 8;

  float s[8] = {0.f, 0.f, 0.f, 0.f, 0.f, 0.f, 0.f, 0.f};
  for (int kh = 0; kh < ksl; kh++) {
    bf16x8 pv = *(const bf16x8*)&part[((size_t)kh << 22) + (size_t)n * 1024 + j];
#pragma unroll
    for (int jj = 0; jj < 8; jj++) s[jj] += bf2f((unsigned short)pv[jj]);
  }
  const float rv = rinv[n];
  float4 bb0 = *(const float4*)&bias[ch * 8];
  float4 bb1 = *(const float4*)&bias[ch * 8 + 4];
  float r[8];
#pragma unroll
  for (int jj = 0; jj < 8; jj++) {
    float bbj = (jj < 4) ? ((const float*)&bb0)[jj] : ((const float*)&bb1)[jj - 4];
    r[jj] = fmaxf(s[jj] * rv + bbj, 0.f);
  }
  float* op = &out[((size_t)b * NSEN + n) * DOUT + ch * 8];
  *(float4*)op       = make_float4(r[0], r[1], r[2], r[3]);
  *(float4*)(op + 4) = make_float4(r[4], r[5], r[6], r[7]);
}

// ---------------- launch -----------------------------------------------------------
extern "C" void kernel_launch(void* const* d_in, const int* in_sizes, int n_in,
                              void* d_out, int out_size, void* d_ws, size_t ws_size,
                              hipStream_t stream) {
  const float* x    = (const float*)d_in[0];
  const float* E1   = (const float*)d_in[1];
  const float* E2   = (const float*)d_in[2];
  const float* W    = (const float*)d_in[3];
  const float* bias = (const float*)d_in[4];
  float* out = (float*)d_out;

  char* ws = (char*)d_ws;
  // layout: adjp 33554432 | yt 8388608 | rinv 16384 | part 33554432  (~76 MiB)
  unsigned short* adjp = (unsigned short*)(ws);
  unsigned short* yt   = (unsigned short*)(ws + 33554432);
  float*          rinv = (float*)(ws + 33554432 + 8388608);
  unsigned short* part = (unsigned short*)(ws + 33554432 + 8388608 + 16384);

  const int KS = 4, nsteps = 128 / KS;   // BK=32: 128 K-steps total

  k_prep<<<dim3(506), dim3(512), 0, stream>>>(E1, E2, W, x, adjp, rinv, yt);
  k_gemm<<<dim3(KS * 16, 4), dim3(512), 0, stream>>>(adjp, yt, part, nsteps);
  k_fin<<<dim3(250, BATCH), dim3(256), 0, stream>>>(part, rinv, bias, out, KS);
}